// Round 3
// baseline (196.772 us; speedup 1.0000x reference)
//
#include <hip/hip_runtime.h>

// ===================== R9: DIAGNOSTIC BUILD (REP=4) =====================
// PQ embedding gather, out[t, m*32+j] = centroids[m, item_codes[ids[t],m], j].
// This round intentionally repeats the ENTIRE (idempotent) kernel body 4x
// inside one dispatch so the kernel's duration exceeds the harness's ~62-66us
// poison-fill dispatches and finally appears in the rocprof top-5 WITH
// counters (FETCH_SIZE / WRITE_SIZE / hbm_gbps / Occupancy / VALUBusy).
//
// Why: R0/R1/R2 (LDS+interleaved, staged, staged+nt-store) all landed within
// fill-variance of each other; our kernel has never been counter-visible.
// Two live worlds:
//   A: kernel ~60-66us (3x off the ~19us roofline) -> kernel row ~240-270us;
//      counters then identify overfetch vs latency vs issue-bound.
//   B: kernel already ~17-25us and dur_us is fill-dominated -> kernel row
//      ~70-100us; next round reverts to single-pass and declares roofline.
// Values written are identical every pass -> absmax unchanged.
// ========================================================================

typedef float f4 __attribute__((ext_vector_type(4)));

#define M_BYTES 8
#define SUB_DIM 32
#define EMB     (M_BYTES * SUB_DIM)   // 256 floats per token
#define TPW     8                     // tokens per wave
#define WAVES   4
#define TOK_PER_BLOCK (TPW * WAVES)   // 32
#define BLOCK   256
#define REP     4                     // DIAGNOSTIC repeat count

__global__ __launch_bounds__(BLOCK) void ItemCodeLayer_30253749633338_kernel(
    const int*   __restrict__ ids,    // [B*S]
    const int*   __restrict__ codes,  // [(N+1)*M]
    const float* __restrict__ cent,   // [M*256*SUB]
    float*       __restrict__ out,    // [B*S*EMB]
    int n_tokens)
{
    const int tid  = threadIdx.x;
    const int l    = tid & 63;
    const int wave = __builtin_amdgcn_readfirstlane(tid >> 6);
    const int lm   = l >> 3;          // code byte handled by this lane group
    const int l4   = l * 4;           // lane's float offset within the token row

    const float* centBase = cent + (size_t)lm * 256 * SUB_DIM + (l & 7) * 4;

    const int t0 = blockIdx.x * TOK_PER_BLOCK + wave * TPW;

    for (int rep = 0; rep < REP; ++rep) {
        if (t0 + TPW <= n_tokens) {
            // Stage 1: 8 independent NT code gathers (random 32 B rows, 32 MB table).
            int c[TPW];
            #pragma unroll
            for (int k = 0; k < TPW; ++k) {
                int id = ids[t0 + k];                       // wave-uniform
                c[k] = __builtin_nontemporal_load(codes + (size_t)id * M_BYTES + lm);
            }
            // Stage 2: 8 centroid gathers (16 B/lane; 128-B line per 8-lane group).
            f4 v[TPW];
            #pragma unroll
            for (int k = 0; k < TPW; ++k)
                v[k] = *reinterpret_cast<const f4*>(centBase + (size_t)c[k] * SUB_DIM);
            // Stage 3: 8 contiguous 1-KB cached stores.
            #pragma unroll
            for (int k = 0; k < TPW; ++k)
                *reinterpret_cast<f4*>(out + (size_t)(t0 + k) * EMB + l4) = v[k];
        } else if (t0 < n_tokens) {
            // guarded tail (not taken at B*S = 102400 = 3200*32)
            #pragma unroll
            for (int k = 0; k < TPW; ++k) {
                int t = t0 + k;
                if (t < n_tokens) {
                    int id  = ids[t];
                    int cd  = codes[(size_t)id * M_BYTES + lm];
                    f4 val  = *reinterpret_cast<const f4*>(centBase + (size_t)cd * SUB_DIM);
                    *reinterpret_cast<f4*>(out + (size_t)t * EMB + l4) = val;
                }
            }
        }
        // Compiler memory barrier: forbid hoisting/merging across reps so each
        // pass truly re-issues its loads and stores (keeps traffic = REP x base).
        asm volatile("" ::: "memory");
    }
}

extern "C" void kernel_launch(void* const* d_in, const int* in_sizes, int n_in,
                              void* d_out, int out_size, void* d_ws, size_t ws_size,
                              hipStream_t stream) {
    const int*   ids   = (const int*)  d_in[0];   // input_ids  [B*S] int32
    const int*   codes = (const int*)  d_in[1];   // item_codes [(N+1)*M] int32
    const float* cent  = (const float*)d_in[2];   // centroids  [M*256*SUB] float32
    float*       out   = (float*)      d_out;

    const int n_tokens = in_sizes[0];             // 102400 tokens
    const int grid = (n_tokens + TOK_PER_BLOCK - 1) / TOK_PER_BLOCK;   // 3200

    hipLaunchKernelGGL(ItemCodeLayer_30253749633338_kernel,
                       dim3(grid), dim3(BLOCK), 0, stream,
                       ids, codes, cent, out, n_tokens);
}

// Round 4
// 137.365 us; speedup vs baseline: 1.4325x; 1.4325x over previous
//
#include <hip/hip_runtime.h>

// PQ embedding gather:
//   out[t, m*32 + j] = centroids[m, item_codes[ids[t], m], j]
// B*S = 102400 tokens, M = 8, SUB = 32, 256 centroids/byte.
//
// R10: persistent waves + 1-deep software pipeline.
// R9 diagnostic (REP=4) established: single-pass kernel ~24-28us vs ~20-23us
// DRAM-physics floor (105 MB write @ 6.7 TB/s demonstrated-by-fill = 15.7us,
// + ~6.5 MB *random* 64-B code-line reads costing ~4-8us of channel time).
// hbm 45%, VALU 3%, occupancy 57%: memory-TIME-bound, not byte/issue-bound.
// Remaining mechanism: waves were 8-KB-lifetime fire-and-die, so random code
// read latency was hidden only by TLP, never overlapped intra-wave with the
// store stream. Here each wave grid-strides over chunks and prefetches chunk
// i+stride's code rows while gathering/storing chunk i:
//   [8 centroid gathers (i)] | sched_barrier | [8 code prefetch (i+stride)]
//   [8 stores (i)] -> rotate
// In-order vmcnt retirement makes each consumption wait exactly vmcnt(8):
// gathers are older than prefetches; prefetches are older than stores.
// sched_barrier(0) stops the compiler hoisting the HBM prefetches above the
// centroid gathers (which would gate gather-retirement behind ~900-cyc loads).
// Grid 1024 = 4 blocks/CU exactly (no tail); 4096 waves x ~3.1 chunks.
//   - nt loads on code rows kept (zero reuse; don't evict centroids).
//   - plain cached stores (nt stores: no win in R2).

typedef float f4 __attribute__((ext_vector_type(4)));

#define M_BYTES 8
#define SUB_DIM 32
#define EMB     (M_BYTES * SUB_DIM)   // 256 floats per token
#define TPW     8                     // tokens per wave-chunk
#define WAVES   4
#define BLOCK   256
#define GRID_BLOCKS 1024              // 4 blocks/CU on 256 CUs

__global__ __launch_bounds__(BLOCK) void ItemCodeLayer_30253749633338_kernel(
    const int*   __restrict__ ids,    // [B*S]
    const int*   __restrict__ codes,  // [(N+1)*M]
    const float* __restrict__ cent,   // [M*256*SUB]
    float*       __restrict__ out,    // [B*S*EMB]
    int n_tokens)
{
    const int tid  = threadIdx.x;
    const int l    = tid & 63;
    const int wave = tid >> 6;
    const int lm   = l >> 3;          // code byte handled by this lane group
    const int l4   = l * 4;           // lane's float offset in the token row

    const float* centBase = cent + (size_t)lm * 256 * SUB_DIM + (l & 7) * 4;

    const int nchunks = (n_tokens + TPW - 1) / TPW;   // 12800
    const int stride  = gridDim.x * WAVES;            // 4096
    int chunk = blockIdx.x * WAVES + wave;
    if (chunk >= nchunks) return;

    const int last = n_tokens - 1;

    // ---- prologue: prefetch code rows for this wave's first chunk
    int c[TPW];
    {
        const int t0 = chunk * TPW;
        #pragma unroll
        for (int k = 0; k < TPW; ++k) {
            int t = t0 + k; if (t > last) t = last;       // clamp (tail-safe)
            int id = ids[t];                              // wave-uniform
            c[k] = __builtin_nontemporal_load(codes + (size_t)id * M_BYTES + lm);
        }
    }

    for (;;) {
        const int t0   = chunk * TPW;
        const int next = chunk + stride;
        const bool have_next = next < nchunks;            // wave-uniform

        // Stage G: centroid gathers for CURRENT chunk — issued first so their
        // in-order vmcnt retirement isn't gated behind next's HBM loads.
        f4 v[TPW];
        #pragma unroll
        for (int k = 0; k < TPW; ++k)
            v[k] = *reinterpret_cast<const f4*>(centBase + (size_t)c[k] * SUB_DIM);

        __builtin_amdgcn_sched_barrier(0);  // pin: prefetch stays AFTER gathers

        // Stage P: prefetch NEXT chunk's code rows (random HBM, ~900 cyc);
        // latency hides under the gather-wait + store issue below.
        int cn[TPW];
        if (have_next) {
            const int tn = next * TPW;
            #pragma unroll
            for (int k = 0; k < TPW; ++k) {
                int t = tn + k; if (t > last) t = last;
                int id = ids[t];
                cn[k] = __builtin_nontemporal_load(codes + (size_t)id * M_BYTES + lm);
            }
        }

        // Stage S: stores for CURRENT chunk (64 lanes x 16 B = 1 KB/token).
        // Consuming v[k] waits vmcnt(8): only the 8 prefetches are younger.
        #pragma unroll
        for (int k = 0; k < TPW; ++k) {
            int t = t0 + k;
            if (t < n_tokens)
                *reinterpret_cast<f4*>(out + (size_t)t * EMB + l4) = v[k];
        }

        if (!have_next) break;
        chunk = next;
        #pragma unroll
        for (int k = 0; k < TPW; ++k) c[k] = cn[k];   // consume waits vmcnt(8)
    }
}

extern "C" void kernel_launch(void* const* d_in, const int* in_sizes, int n_in,
                              void* d_out, int out_size, void* d_ws, size_t ws_size,
                              hipStream_t stream) {
    const int*   ids   = (const int*)  d_in[0];   // input_ids  [B*S] int32
    const int*   codes = (const int*)  d_in[1];   // item_codes [(N+1)*M] int32
    const float* cent  = (const float*)d_in[2];   // centroids  [M*256*SUB] float32
    float*       out   = (float*)      d_out;

    const int n_tokens = in_sizes[0];             // 102400 tokens
    const int nchunks  = (n_tokens + TPW - 1) / TPW;
    int grid = (nchunks + WAVES - 1) / WAVES;
    if (grid > GRID_BLOCKS) grid = GRID_BLOCKS;

    hipLaunchKernelGGL(ItemCodeLayer_30253749633338_kernel,
                       dim3(grid), dim3(BLOCK), 0, stream,
                       ids, codes, cent, out, n_tokens);
}

// Round 5
// 128.742 us; speedup vs baseline: 1.5284x; 1.0670x over previous
//
#include <hip/hip_runtime.h>
#include <hip/hip_bf16.h>

// PQ embedding gather:
//   out[t, m*32 + j] = centroids[m, item_codes[ids[t], m], j]
// B*S = 102400 tokens, M = 8 code bytes, SUB = 32 floats, 256 centroids/byte.
//   ids:       int32   [B*S]
//   item_codes:int32   [(N+1)*8]    (32 MB, random-row gather -> latency hazard)
//   centroids: float32 [8*256*32]   (256 KB, L2-resident)
//   out:       float32 [B*S*256]    (105 MB, streaming coalesced write)
//
// R11 = REVERT to the R0/harness-best structure (128.5 us measured).
// Session ledger (overhead-normalized kernel times; harness fill/reset adds
// a fixed ~100 us to every dur_us):
//   R0  this structure (Phase-A MLP=32 lines/wave)      ~28.5 us  <- best
//   R1  staged barrier-free (8 lines/wave)              ~33 us
//   R2  staged + nt stores                              ~34 us
//   R3  REP=4 diagnostic: counters visible -> hbm 3.7 TB/s, VALU 3%,
//       occupancy 57%, 0 bank conflicts; ~24 us/pass warm
//   R4  persistent + 1-deep pipeline (8 lines/wave)     ~37 us    <- worst
// Conclusion: random-read latency hiding is purely outstanding-miss count.
// Phase A below issues ONE independent 16 B line per LANE (32 distinct rows
// per wave, 128 per block, ~400 in flight per CU) -- every restructure that
// "improved" scheduling cut this 4x and lost 5-9 us. Keep it.
//
// 128 tokens / 256-thread block (grid 800).
//   Phase A: each thread issues ONE independent 16 B (dwordx4) nontemporal
//            load = half a code row; 128 random lines in flight per block.
//   Phase B: each wave writes 32 tokens (1 KB each), unroll x8 independent
//            centroid-gather/store chains; plain (cached) stores.
//            (nt stores tested R2: no win. Staging tested R1: loss.)

typedef float f4  __attribute__((ext_vector_type(4)));
typedef int   v4i __attribute__((ext_vector_type(4)));

#define M_BYTES 8
#define SUB_DIM 32
#define EMB     (M_BYTES * SUB_DIM)   // 256 floats per token
#define TOK_PER_BLOCK 128
#define BLOCK 256

__global__ __launch_bounds__(BLOCK) void ItemCodeLayer_30253749633338_kernel(
    const int*   __restrict__ ids,    // [B*S]
    const int*   __restrict__ codes,  // [(N+1)*M]
    const float* __restrict__ cent,   // [M*256*SUB]
    float*       __restrict__ out,    // [B*S*EMB]
    int n_tokens)
{
    __shared__ int s_codes[TOK_PER_BLOCK * M_BYTES];   // 4 KB

    const int tid  = threadIdx.x;
    const int base = blockIdx.x * TOK_PER_BLOCK;

    // ---- Phase A: 128 code rows, one independent 16 B chunk per thread.
    {
        const int tA = tid >> 1;          // 0..127 : token within block
        const int h  = tid & 1;           // 0/1    : which 16 B half of the 32 B row
        int id = (base + tA < n_tokens) ? ids[base + tA] : 0;   // 2 lanes share id line
        // Random 32 B rows in the 32 MB table; zero reuse -> nontemporal load.
        v4i row = __builtin_nontemporal_load(
            reinterpret_cast<const v4i*>(codes + (size_t)id * M_BYTES + h * 4));
        *reinterpret_cast<v4i*>(&s_codes[tA * M_BYTES + h * 4]) = row;
    }
    __syncthreads();

    // ---- Phase B: each wave streams 32 tokens (1 KB per token), unroll x8.
    const int wave = tid >> 6;            // 0..3
    const int l    = tid & 63;
    const int lm   = l >> 3;              // code byte handled by this lane
    const int lj   = (l & 7) * 4;         // float offset within sub-embedding
    const float* centBase = cent + (size_t)lm * 256 * SUB_DIM + lj;

    #pragma unroll
    for (int it = 0; it < 32; it += 8) {
        int tk[8];
        f4  v[8];
        #pragma unroll
        for (int u = 0; u < 8; ++u) {
            tk[u] = wave * 32 + it + u;                  // 0..127, disjoint per wave
            int code = s_codes[tk[u] * M_BYTES + lm];    // LDS broadcast (8 lanes/addr)
            v[u] = *reinterpret_cast<const f4*>(centBase + (size_t)code * SUB_DIM);
        }
        #pragma unroll
        for (int u = 0; u < 8; ++u) {
            int t = base + tk[u];
            if (t < n_tokens) {
                // 64 lanes -> contiguous 1 KB cached store
                *reinterpret_cast<f4*>(
                    out + ((size_t)t * EMB + lm * SUB_DIM + lj)) = v[u];
            }
        }
    }
}

extern "C" void kernel_launch(void* const* d_in, const int* in_sizes, int n_in,
                              void* d_out, int out_size, void* d_ws, size_t ws_size,
                              hipStream_t stream) {
    const int*   ids   = (const int*)  d_in[0];   // input_ids  [B*S] int32
    const int*   codes = (const int*)  d_in[1];   // item_codes [(N+1)*M] int32
    const float* cent  = (const float*)d_in[2];   // centroids  [M*256*SUB] float32
    float*       out   = (float*)      d_out;

    const int n_tokens = in_sizes[0];             // 102400 tokens
    const int grid = (n_tokens + TOK_PER_BLOCK - 1) / TOK_PER_BLOCK;   // 800

    hipLaunchKernelGGL(ItemCodeLayer_30253749633338_kernel,
                       dim3(grid), dim3(BLOCK), 0, stream,
                       ids, codes, cent, out, n_tokens);
}